// Round 3
// baseline (201.052 us; speedup 1.0000x reference)
//
#include <hip/hip_runtime.h>
#include <hip/hip_bf16.h>

// SimCLR NT-Xent loss. B=4096, D=256, N=2B=8192 rows.
// loss = (1/N) sum_i [ log(denom_i) - log(pos_i) ]
//   denom_i = sum_{j!=i} exp(2*sim_ij),  pos_i = cos(z_i, z_{i+-B}) (fp32 path)
//
// denom: fp8(e4m3) sim-GEMM via mfma_scale_f32_16x16x128_f8f6f4 (unit scales).
// A-tile (64 rows x K=256) resident in VGPRs for the whole j-sweep (no LDS, no
// barrier for A). B staged in 32 KB LDS per 128-j tile, XOR-swizzled. exp
// row-sums accumulate in registers across the j-loop; 128 atomics per block.

#define NROWS 8192
#define BHALF 4096
#define DDIM  256
#define JCHUNK 512
#define JITERS (JCHUNK / 128)   // 4

typedef __attribute__((ext_vector_type(4))) int   i32x4;
typedef __attribute__((ext_vector_type(8))) int   i32x8;
typedef __attribute__((ext_vector_type(4))) float f32x4;

#define SCALE1 0x7F7F7F7F   // e8m0 biased-127 = 2^0 in every byte

__device__ __forceinline__ void load_lds16(const unsigned char* g, unsigned char* l) {
    __builtin_amdgcn_global_load_lds(
        (const __attribute__((address_space(1))) void*)g,
        (__attribute__((address_space(3))) void*)l, 16, 0, 0);
}

// Kernel 1: norms + fp8-normalized matrix + positive cosine (fp32) + denom=0.
__global__ __launch_bounds__(256) void prep_kernel(const float* __restrict__ z1,
                                                   const float* __restrict__ z2,
                                                   unsigned char* __restrict__ zn8,
                                                   float* __restrict__ pos,
                                                   float* __restrict__ denom) {
    int i    = blockIdx.x * 4 + (threadIdx.x >> 6);
    int lane = threadIdx.x & 63;
    float4 a = reinterpret_cast<const float4*>(z1 + (size_t)i * DDIM)[lane];
    float4 b = reinterpret_cast<const float4*>(z2 + (size_t)i * DDIM)[lane];
    float ss1 = a.x * a.x + a.y * a.y + a.z * a.z + a.w * a.w;
    float ss2 = b.x * b.x + b.y * b.y + b.z * b.z + b.w * b.w;
    float dd  = a.x * b.x + a.y * b.y + a.z * b.z + a.w * b.w;
    #pragma unroll
    for (int off = 32; off; off >>= 1) {
        ss1 += __shfl_xor(ss1, off);
        ss2 += __shfl_xor(ss2, off);
        dd  += __shfl_xor(dd, off);
    }
    float n1 = fmaxf(sqrtf(ss1), 1e-8f);
    float n2 = fmaxf(sqrtf(ss2), 1e-8f);
    float i1 = 1.0f / n1, i2 = 1.0f / n2;
    int pa = __builtin_amdgcn_cvt_pk_fp8_f32(a.x * i1, a.y * i1, 0, 0);
    pa     = __builtin_amdgcn_cvt_pk_fp8_f32(a.z * i1, a.w * i1, pa, 1);
    int pb = __builtin_amdgcn_cvt_pk_fp8_f32(b.x * i2, b.y * i2, 0, 0);
    pb     = __builtin_amdgcn_cvt_pk_fp8_f32(b.z * i2, b.w * i2, pb, 1);
    reinterpret_cast<int*>(zn8 + (size_t)i * DDIM)[lane] = pa;
    reinterpret_cast<int*>(zn8 + (size_t)(i + BHALF) * DDIM)[lane] = pb;
    if (lane == 0) pos[i] = dd * i1 * i2;
    if (threadIdx.x < 8) denom[blockIdx.x * 8 + threadIdx.x] = 0.0f;
}

// Kernel 2: fp8 MFMA sim-GEMM + exp row-sum.
// Block: 256 thr, waves 2x2 over a 128-i x 128-j tile; j-loop over JITERS
// tiles. A-frags in registers across the whole kernel.
__global__ __launch_bounds__(256, 2) void denom_kernel(const unsigned char* __restrict__ zn8,
                                                       float* __restrict__ denom) {
    __shared__ __align__(16) unsigned char sB[128 * DDIM];   // 32 KB

    int t    = threadIdx.x;
    int lane = t & 63;
    int wave = t >> 6;
    int col  = lane & 15;
    int quad = lane >> 4;
    int wm = wave >> 1, wn = wave & 1;
    int iBase = blockIdx.y * 128;
    int jt0   = blockIdx.x * JCHUNK;

    // ---- A fragments: 4 mt x 2 ks, 32 contiguous k-bytes per lane ----
    i32x8 afrag[4][2];
    {
        const unsigned char* aRow = zn8 + (size_t)(iBase + wm * 64 + col) * DDIM + quad * 32;
        #pragma unroll
        for (int mt = 0; mt < 4; mt++)
            #pragma unroll
            for (int ks = 0; ks < 2; ks++) {
                const i32x4* p = (const i32x4*)(aRow + mt * 16 * DDIM + ks * 128);
                i32x4 lo = p[0], hi = p[1];
                i32x8 f;
                f[0] = lo[0]; f[1] = lo[1]; f[2] = lo[2]; f[3] = lo[3];
                f[4] = hi[0]; f[5] = hi[1]; f[6] = hi[2]; f[7] = hi[3];
                afrag[mt][ks] = f;
            }
    }

    // ---- sB staging addresses (granule-XOR swizzle) ----
    // granule id = s*256 + wave*64 + lane; row r = id>>4, pos p = id&15;
    // global chunk = p ^ (r&15); r&15 == wave*4+quad (s-invariant).
    int rowInWave = wave * 4 + quad;
    int swz = col ^ rowInWave;
    const unsigned char* gB0 = zn8 + (size_t)(jt0 + rowInWave) * DDIM + swz * 16;
    unsigned char* lB = sB + wave * 1024 + lane * 16;

    // ---- B fragment read offsets ----
    // row = wn*64 + nt*16 + col; granule g = ks*8 + quad*2 + b; pos = g ^ col
    int rowb = (wn * 64 + col) * DDIM;
    int po[4];
    #pragma unroll
    for (int ks = 0; ks < 2; ks++)
        #pragma unroll
        for (int b = 0; b < 2; b++)
            po[ks * 2 + b] = ((ks * 8 + quad * 2 + b) ^ col) * 16;

    float rs[4][4];
    #pragma unroll
    for (int mt = 0; mt < 4; mt++)
        #pragma unroll
        for (int r = 0; r < 4; r++) rs[mt][r] = 0.f;

    for (int jj = 0; jj < JITERS; jj++) {
        int jt = jt0 + jj * 128;
        const unsigned char* g = gB0 + (size_t)jj * 128 * DDIM;
        #pragma unroll
        for (int s = 0; s < 8; s++)
            load_lds16(g + s * 16 * DDIM, lB + s * 4096);
        __syncthreads();

        #pragma unroll
        for (int nt = 0; nt < 4; nt++) {
            const unsigned char* bbase = sB + rowb + nt * 16 * DDIM;
            i32x4 l0 = *(const i32x4*)(bbase + po[0]);
            i32x4 h0 = *(const i32x4*)(bbase + po[1]);
            i32x4 l1 = *(const i32x4*)(bbase + po[2]);
            i32x4 h1 = *(const i32x4*)(bbase + po[3]);
            i32x8 b0, b1;
            b0[0] = l0[0]; b0[1] = l0[1]; b0[2] = l0[2]; b0[3] = l0[3];
            b0[4] = h0[0]; b0[5] = h0[1]; b0[6] = h0[2]; b0[7] = h0[3];
            b1[0] = l1[0]; b1[1] = l1[1]; b1[2] = l1[2]; b1[3] = l1[3];
            b1[4] = h1[0]; b1[5] = h1[1]; b1[6] = h1[2]; b1[7] = h1[3];

            #pragma unroll
            for (int mt = 0; mt < 4; mt++) {
                f32x4 acc = {0.f, 0.f, 0.f, 0.f};
                acc = __builtin_amdgcn_mfma_scale_f32_16x16x128_f8f6f4(
                          afrag[mt][0], b0, acc, 0, 0, 0, SCALE1, 0, SCALE1);
                acc = __builtin_amdgcn_mfma_scale_f32_16x16x128_f8f6f4(
                          afrag[mt][1], b1, acc, 0, 0, 0, SCALE1, 0, SCALE1);
                bool dtile = (iBase + wm * 64 + mt * 16) == (jt + wn * 64 + nt * 16);
                if (dtile) {
                    #pragma unroll
                    for (int r = 0; r < 4; r++) {
                        float e = __expf(2.0f * acc[r]);
                        rs[mt][r] += (quad * 4 + r == col) ? 0.f : e;
                    }
                } else {
                    #pragma unroll
                    for (int r = 0; r < 4; r++)
                        rs[mt][r] += __expf(2.0f * acc[r]);
                }
            }
        }
        __syncthreads();
    }

    // ---- reduce over the 16 column-lanes, combine wn pair via LDS ----
    #pragma unroll
    for (int mt = 0; mt < 4; mt++)
        #pragma unroll
        for (int r = 0; r < 4; r++) {
            float x = rs[mt][r];
            x += __shfl_xor(x, 1);
            x += __shfl_xor(x, 2);
            x += __shfl_xor(x, 4);
            x += __shfl_xor(x, 8);
            rs[mt][r] = x;
        }
    __syncthreads();
    float* red = (float*)sB;
    if (col == 0) {
        #pragma unroll
        for (int mt = 0; mt < 4; mt++)
            #pragma unroll
            for (int r = 0; r < 4; r++)
                red[wn * 128 + wm * 64 + mt * 16 + quad * 4 + r] = rs[mt][r];
    }
    __syncthreads();
    if (t < 128)
        atomicAdd(&denom[iBase + t], red[t] + red[128 + t]);
}

// Kernel 3: final scalar reduction (pos entries each count twice).
__global__ __launch_bounds__(256) void loss_kernel(const float* __restrict__ pos,
                                                   const float* __restrict__ denom,
                                                   float* __restrict__ out) {
    __shared__ float sdata[4];
    float s = 0.f;
    for (int i = threadIdx.x; i < NROWS; i += 256)
        s += __logf(denom[i]);
    for (int i = threadIdx.x; i < BHALF; i += 256)
        s -= 2.0f * __logf(pos[i]);
    #pragma unroll
    for (int off = 32; off; off >>= 1) s += __shfl_xor(s, off);
    if ((threadIdx.x & 63) == 0) sdata[threadIdx.x >> 6] = s;
    __syncthreads();
    if (threadIdx.x == 0)
        out[0] = (sdata[0] + sdata[1] + sdata[2] + sdata[3]) * (1.0f / NROWS);
}

extern "C" void kernel_launch(void* const* d_in, const int* in_sizes, int n_in,
                              void* d_out, int out_size, void* d_ws, size_t ws_size,
                              hipStream_t stream) {
    const float* z1 = (const float*)d_in[0];
    const float* z2 = (const float*)d_in[1];

    // ws: zn8 fp8 [8192*256] (2 MB) | pos f32[4096] | denom f32[8192]
    unsigned char* zn8 = (unsigned char*)d_ws;
    float* pos   = (float*)((char*)d_ws + (size_t)NROWS * DDIM);
    float* denom = pos + BHALF;

    prep_kernel<<<BHALF / 4, 256, 0, stream>>>(z1, z2, zn8, pos, denom);
    denom_kernel<<<dim3(NROWS / JCHUNK, NROWS / 128), 256, 0, stream>>>(zn8, denom);
    loss_kernel<<<1, 256, 0, stream>>>(pos, denom, (float*)d_out);
}